// Round 6
// baseline (144088.733 us; speedup 1.0000x reference)
//
#include <hip/hip_runtime.h>
#include <math.h>

// h_t = tanh(A h_{t-1} + B x_t + c), A = 0.9 I + 0.1 A_raw
// T=16384, X=512, H=1024, fp32. Output: all h_t, [T, H].
//
// Phase 1: Bx = x @ B^T + c written in-place into d_out (row t consumed once
//          at step t, then overwritten with h_t).
// Phase 2: XCD-LOCAL tagged-slot scan.
//   - The h exchange is latency-bound on the interconnect round trip. LLC
//     (device-coherent) RT is ~800-900 cy (rounds 3-5); a single XCD's L2 is
//     coherent within the XCD at ~200 cy. So: elect one XCD, run the whole
//     scan on its 32 CUs, exchange h through its L2.
//   - Election: 256 blocks x 512 threads (all co-resident by capacity).
//     Each block reads HW_REG_XCC_ID, tickets atomically per XCD; pigeonhole
//     guarantees some XCD gets >=32 blocks; 32nd block CASes the winner.
//     Non-winner blocks exit. 32 winner blocks x 32 rows cover H=1024.
//   - Tagged 4-deep ring of (fp32,tag) 8B packets, as validated rounds 3-5.
//     Producers dual-store: fast ring (sc0 -> winner L2) + LLC mirror ring
//     (sc0 sc1). Consumers poll the fast ring with dwordx4 sc0 (L1 bypass,
//     L2 hit); sticky timeout falls back to the LLC ring, so a broken
//     L2-coherence assumption degrades to round-4 behavior, not deadlock.
//   - Per step: poll 2 slots -> padded LDS -> barrier -> 64 FMA/thread with
//     LDS broadcast reads -> shfl_xor(32) -> partials to LDS -> barrier ->
//     tail (tid<32): sum 8 partials + Bx, tanh, store out + both rings.
//   - Skew <= 1 step by dataflow; ring depth 4 => no overwrite of live data.

#define T_STEPS 16384
#define XD 512
#define HD 1024
#define KBLOCKS 32     // winner replica size (pigeonhole-safe with 256 blocks)

typedef unsigned int uint32x4 __attribute__((ext_vector_type(4)));
typedef unsigned int uint32x2 __attribute__((ext_vector_type(2)));

union fu { float f; unsigned u; };

__device__ __forceinline__ float fast_tanh(float x) {
    // tanh(x) = 1 - 2/(exp(2x)+1); v_exp + v_rcp, branchless, ~1e-7 abs err.
    const float e = __expf(2.0f * x);
    return 1.0f - 2.0f * __builtin_amdgcn_rcpf(e + 1.0f);
}

// ---------------------------------------------------------------------------
// Phase 1: GEMM  out[t][i] = sum_k x[t][k] * B[i][k] + c[i]
// 64x64 tile, 256 threads, 4x4 micro-tile per thread, K-chunk 32.
// ---------------------------------------------------------------------------
__global__ __launch_bounds__(256) void gemm_bx_kernel(
    const float* __restrict__ x, const float* __restrict__ B,
    const float* __restrict__ c, float* __restrict__ out)
{
    __shared__ __align__(16) float xs[32][68];  // [k][t]
    __shared__ __align__(16) float bs[32][68];  // [k][i]

    const int tid = threadIdx.x;
    const int t0 = blockIdx.x * 64;
    const int i0 = blockIdx.y * 64;
    const int tx = tid & 15;
    const int ty = tid >> 4;
    const int lr = tid >> 3;
    const int lc = (tid & 7) << 2;

    float acc[4][4] = {{0.f}};

    for (int k0 = 0; k0 < XD; k0 += 32) {
        const float4 xa = *(const float4*)&x[(size_t)(t0 + lr) * XD + k0 + lc];
        const float4 xb = *(const float4*)&x[(size_t)(t0 + lr + 32) * XD + k0 + lc];
        const float4 ba = *(const float4*)&B[(size_t)(i0 + lr) * XD + k0 + lc];
        const float4 bb = *(const float4*)&B[(size_t)(i0 + lr + 32) * XD + k0 + lc];
        __syncthreads();
        xs[lc + 0][lr] = xa.x; xs[lc + 1][lr] = xa.y; xs[lc + 2][lr] = xa.z; xs[lc + 3][lr] = xa.w;
        xs[lc + 0][lr + 32] = xb.x; xs[lc + 1][lr + 32] = xb.y; xs[lc + 2][lr + 32] = xb.z; xs[lc + 3][lr + 32] = xb.w;
        bs[lc + 0][lr] = ba.x; bs[lc + 1][lr] = ba.y; bs[lc + 2][lr] = ba.z; bs[lc + 3][lr] = ba.w;
        bs[lc + 0][lr + 32] = bb.x; bs[lc + 1][lr + 32] = bb.y; bs[lc + 2][lr + 32] = bb.z; bs[lc + 3][lr + 32] = bb.w;
        __syncthreads();
        #pragma unroll
        for (int k = 0; k < 32; ++k) {
            const float4 av = *(const float4*)&xs[k][ty << 2];
            const float4 bv = *(const float4*)&bs[k][tx << 2];
            const float am[4] = {av.x, av.y, av.z, av.w};
            const float bn[4] = {bv.x, bv.y, bv.z, bv.w};
            #pragma unroll
            for (int m = 0; m < 4; ++m)
                #pragma unroll
                for (int n = 0; n < 4; ++n)
                    acc[m][n] = fmaf(am[m], bn[n], acc[m][n]);
        }
    }

    #pragma unroll
    for (int m = 0; m < 4; ++m) {
        const int trow = t0 + (ty << 2) + m;
        #pragma unroll
        for (int n = 0; n < 4; ++n) {
            const int icol = i0 + (tx << 2) + n;
            out[(size_t)trow * HD + icol] = acc[m][n] + c[icol];
        }
    }
}

// ---------------------------------------------------------------------------
// Workspace init (d_ws is poisoned 0xAA before every launch).
// Fast ring [0..4096) slots, LLC mirror ring [4096..8192) slots, then ctrl:
// ctrl[0..7] = per-XCD tickets, ctrl[8] = winner (-1).
// ---------------------------------------------------------------------------
__global__ void init_ws_kernel(unsigned long long* slots, const float* h0,
                               int* ctrl)
{
    const int i = threadIdx.x;  // 1024 threads
    fu v; v.f = h0[i];
    const unsigned long long h0pkt = (unsigned long long)v.u;  // tag 0
    const unsigned long long inv   = 0xFFFFFFFF00000000ull;
    slots[0 * HD + i] = inv;
    slots[1 * HD + i] = inv;
    slots[2 * HD + i] = inv;
    slots[3 * HD + i] = h0pkt;
    slots[4096 + 0 * HD + i] = inv;
    slots[4096 + 1 * HD + i] = inv;
    slots[4096 + 2 * HD + i] = inv;
    slots[4096 + 3 * HD + i] = h0pkt;
    if (i < 8) ctrl[i] = 0;
    if (i == 8) ctrl[8] = -1;
}

// ---------------------------------------------------------------------------
// Phase 2: XCD-local tagged-slot scan. Launch 256 blocks x 512 threads;
// 32 blocks on the elected XCD survive. Row r = 32*ticket + (tid&31).
// ---------------------------------------------------------------------------
__global__ __launch_bounds__(512) void rnn_scan_kernel(
    const float* __restrict__ A_raw, float* __restrict__ out,
    unsigned long long* slots, int* ctrl)
{
    const int tid = threadIdx.x;

    // ---- XCD election ----
    unsigned xcc;
    asm volatile("s_getreg_b32 %0, hwreg(HW_REG_XCC_ID)" : "=s"(xcc));
    __shared__ int s_ticket;
    if (tid == 0)
        s_ticket = __hip_atomic_fetch_add(&ctrl[xcc], 1, __ATOMIC_RELAXED,
                                          __HIP_MEMORY_SCOPE_AGENT);
    __syncthreads();
    const int ticket = s_ticket;
    if (ticket == KBLOCKS - 1) {  // this block completes a replica: claim win
        int expected = -1;
        __hip_atomic_compare_exchange_strong(&ctrl[8], &expected, (int)xcc,
            __ATOMIC_RELAXED, __ATOMIC_RELAXED, __HIP_MEMORY_SCOPE_AGENT);
    }
    int win;
    do {
        win = __hip_atomic_load(&ctrl[8], __ATOMIC_RELAXED,
                                __HIP_MEMORY_SCOPE_AGENT);
    } while (win < 0);
    if (win != (int)xcc || ticket >= KBLOCKS) return;

    // ---- participant setup ----
    const int wave = tid >> 6;
    const int lane = tid & 63;
    const int r = tid & 31;          // row within block
    const int cch = tid >> 5;        // k-chunk 0..15 (64 cols each)
    const int R0 = ticket * 32;
    const int grow = R0 + r;

    __shared__ float hs[HD + 64];    // padded: addr(k) = k + 2*(k>>5)
    __shared__ float part[8][32];

    // A_eff[grow][64*cch + i], i = 0..63
    float aw[64];
    #pragma unroll
    for (int i = 0; i < 64; ++i) {
        const int k = (cch << 6) + i;
        float v = 0.1f * A_raw[(size_t)grow * HD + k];
        if (k == grow) v += 0.9f;
        aw[i] = v;
    }

    float bx = (tid < 32) ? out[R0 + tid] : 0.f;

    bool llc_mode = false;

    for (int t = 0; t < T_STEPS; ++t) {
        const unsigned tagw = (unsigned)t;

        // Poll my 2 slots of h_{t-1}: ring[(t+3)&3], tag t. One dwordx4.
        const char* base = (const char*)slots + (llc_mode ? 32768 : 0)
                         + (((t + 3) & 3) << 13) + (tid << 4);
        uint32x4 s;
        int spins = 0;
        for (;;) {
            if (!llc_mode)
                asm volatile(
                    "global_load_dwordx4 %0, %1, off sc0\n\t"
                    "s_waitcnt vmcnt(0)" : "=v"(s) : "v"(base));
            else
                asm volatile(
                    "global_load_dwordx4 %0, %1, off sc0 sc1\n\t"
                    "s_waitcnt vmcnt(0)" : "=v"(s) : "v"(base));
            if (s.y == tagw && s.w == tagw) break;
            if (__any(++spins > (1 << 16)) && !llc_mode) {
                llc_mode = true;   // sticky fallback to LLC mirror ring
                base += 32768;
            }
        }
        fu v0, v1; v0.u = s.x; v1.u = s.z;
        *(float2*)&hs[(tid << 1) + ((tid >> 4) << 1)] = make_float2(v0.f, v1.f);
        __syncthreads();

        // 64 FMA from LDS broadcast reads (2 addrs/instr, pad keeps banks apart)
        const int hb0 = 68 * cch;       // i in [0,32)
        const int hb1 = 68 * cch + 34;  // i in [32,64)
        float p = 0.f;
        #pragma unroll
        for (int j = 0; j < 16; ++j) {
            const float2 ha = *(const float2*)&hs[hb0 + (j << 1)];
            const float2 hb = *(const float2*)&hs[hb1 + (j << 1)];
            p = fmaf(aw[2 * j], ha.x, p);
            p = fmaf(aw[2 * j + 1], ha.y, p);
            p = fmaf(aw[32 + 2 * j], hb.x, p);
            p = fmaf(aw[33 + 2 * j], hb.y, p);
        }
        // lanes l and l^32 hold the same row's two half-partials
        p += __shfl_xor(p, 32, 64);
        if (lane < 32) part[wave][lane] = p;
        __syncthreads();

        // Tail: one thread per row finishes (8 partials + Bx, tanh, stores).
        if (tid < 32) {
            float tot = part[0][tid];
            #pragma unroll
            for (int w2 = 1; w2 < 8; ++w2) tot += part[w2][tid];
            const float h = fast_tanh(tot + bx);
            out[(size_t)t * HD + R0 + tid] = h;
            fu hu; hu.f = h;
            uint32x2 pkt; pkt.x = hu.u; pkt.y = (unsigned)(t + 1);
            char* fp = (char*)slots + ((size_t)(t & 3) << 13)
                     + ((size_t)(R0 + tid) << 3);
            asm volatile("global_store_dwordx2 %0, %1, off sc0"
                         :: "v"(fp), "v"(pkt) : "memory");
            asm volatile("global_store_dwordx2 %0, %1, off sc0 sc1"
                         :: "v"(fp + 32768), "v"(pkt) : "memory");
            if (t + 1 < T_STEPS)
                bx = out[(size_t)(t + 1) * HD + R0 + tid];  // Bx prefetch
        }
        // hs rewrite for t+1 is safe: all hs reads complete before the
        // part-write barrier; part rewrite waits on next step's barrier,
        // which wave 0 only reaches after the tail. Ring depth 4 + skew<=1
        // (dataflow) => no live-data overwrite.
    }
}

// ---------------------------------------------------------------------------
extern "C" void kernel_launch(void* const* d_in, const int* in_sizes, int n_in,
                              void* d_out, int out_size, void* d_ws, size_t ws_size,
                              hipStream_t stream)
{
    const float* x     = (const float*)d_in[0];  // [16384, 512]
    const float* h0    = (const float*)d_in[1];  // [1024]
    const float* A_raw = (const float*)d_in[2];  // [1024, 1024]
    const float* B     = (const float*)d_in[3];  // [1024, 512]
    const float* c     = (const float*)d_in[4];  // [1024]
    float* out = (float*)d_out;                  // [16384, 1024]
    unsigned long long* slots = (unsigned long long*)d_ws;  // 8192 x 8B rings
    int* ctrl = (int*)(slots + 8192);            // tickets[8] + winner

    dim3 gemm_grid(T_STEPS / 64, HD / 64);       // 256 x 16
    gemm_bx_kernel<<<gemm_grid, 256, 0, stream>>>(x, B, c, out);
    init_ws_kernel<<<1, HD, 0, stream>>>(slots, h0, ctrl);
    rnn_scan_kernel<<<256, 512, 0, stream>>>(A_raw, out, slots, ctrl);
}